// Round 4
// baseline (9154.508 us; speedup 1.0000x reference)
//
#include <hip/hip_runtime.h>
#include <hip/hip_bf16.h>

// ---------------- problem constants ----------------
#define TOKENS   65536      // B*N = 32*2048
#define DDIM     512
#define NQ       8
#define NCODES   1024
#define COMMIT_W 0.02

// ---------------- tiling ----------------
#define MT       32         // tokens per block
#define NCHUNK   256        // codes per chunk (4 chunks of 1024)
#define KCH      8          // k-depth per LDS staging step
#define NBLOCKS  (TOKENS / MT)   // 2048
#define KSPLIT   384        // OpenBLAS sgemm K-panel split (SGEMM_DEFAULT_Q)

// out buffer layout (fp32 elements): [quantized][indices][losses][total]
#define OFF_IDX  ((size_t)TOKENS * DDIM)                 // 33,554,432
#define OFF_LOSS (OFF_IDX + (size_t)TOKENS * NQ)         // 34,078,720
#define OFF_TOT  (OFF_LOSS + NQ)                         // 34,078,728

__device__ __forceinline__ bool better(float d, int i, float bd, int bi) {
  return (d < bd) || (d == bd && i < bi);
}

// numpy pairwise leaf: 8-accumulator sum of fl(a[k]^2), n=128, row-major
__device__ __forceinline__ float pw128_row_sq(const float* __restrict__ a) {
  float r0 = __fmul_rn(a[0], a[0]), r1 = __fmul_rn(a[1], a[1]);
  float r2 = __fmul_rn(a[2], a[2]), r3 = __fmul_rn(a[3], a[3]);
  float r4 = __fmul_rn(a[4], a[4]), r5 = __fmul_rn(a[5], a[5]);
  float r6 = __fmul_rn(a[6], a[6]), r7 = __fmul_rn(a[7], a[7]);
  for (int i = 8; i < 128; i += 8) {
    r0 = __fadd_rn(r0, __fmul_rn(a[i + 0], a[i + 0]));
    r1 = __fadd_rn(r1, __fmul_rn(a[i + 1], a[i + 1]));
    r2 = __fadd_rn(r2, __fmul_rn(a[i + 2], a[i + 2]));
    r3 = __fadd_rn(r3, __fmul_rn(a[i + 3], a[i + 3]));
    r4 = __fadd_rn(r4, __fmul_rn(a[i + 4], a[i + 4]));
    r5 = __fadd_rn(r5, __fmul_rn(a[i + 5], a[i + 5]));
    r6 = __fadd_rn(r6, __fmul_rn(a[i + 6], a[i + 6]));
    r7 = __fadd_rn(r7, __fmul_rn(a[i + 7], a[i + 7]));
  }
  return __fadd_rn(__fadd_rn(__fadd_rn(r0, r1), __fadd_rn(r2, r3)),
                   __fadd_rn(__fadd_rn(r4, r5), __fadd_rn(r6, r7)));
}

// ---------------- prep: ee = np-pairwise fp32 ||e||^2 + zero loss accumulators ----
__global__ void prep_kernel(const float* __restrict__ cb, float* __restrict__ eef,
                            double* __restrict__ lossAcc) {
  const int code = blockIdx.x * blockDim.x + threadIdx.x;   // 32 x 256 = 8192
  if (code == 0) {
#pragma unroll
    for (int j = 0; j < NQ; ++j) lossAcc[j] = 0.0;
  }
  if (code < NQ * NCODES) {
    const float* e = cb + (size_t)code * DDIM;
    const float p0 = pw128_row_sq(e), p1 = pw128_row_sq(e + 128);
    const float p2 = pw128_row_sq(e + 256), p3 = pw128_row_sq(e + 384);
    eef[code] = __fadd_rn(__fadd_rn(p0, p1), __fadd_rn(p2, p3));  // np pw512 tree
  }
}

// ---------------- main fused RVQ kernel ----------------
// One block owns MT=32 tokens through all 8 rounds.
//  - faithful np-fp32 residual chain lives (transposed) in LDS; screen GEMM reads it
//  - fp32 screen -> top-4 candidates (sorted-4 insert + cross-lane bitonic merge)
//  - rescore computes the np-faithful fp32 distance for the 4 candidates:
//      rr = np-pairwise sum(r*r); cross = seq-k FMA chain split at KSPLIT (sgemm);
//      d  = fl(fl(rr - 2*cross) + ee); argmin = first-min
//  - residual update / quantized_out replay use the exact np elementwise fp32 ops
__global__ void __launch_bounds__(256, 2)
rvq_main(const float* __restrict__ x, const float* __restrict__ cb,
         const float* __restrict__ eef, double* __restrict__ lossAcc,
         float* __restrict__ outq, float* __restrict__ outidx) {
  __shared__ float  r_t[DDIM * MT];      // 64 KB, residual transposed [k][tm]
  __shared__ float  bt[KCH * NCHUNK];    // 8 KB, codebook stage [kk][c]
  __shared__ int    bcand[MT * 4];       // top-4 candidate indices per token
  __shared__ int    hist[MT][NQ];
  __shared__ double wred[4];

  const int tid  = threadIdx.x;
  const int cg   = tid & 31;   // code group: 8 codes (two float4 spans)
  const int tg   = tid >> 5;   // token group: tokens tg*4 .. tg*4+3
  const int tokR = tid >> 3;   // update mapping: token
  const int part = tid & 7;    //   ... and its 1/8 slice of D
  const int blockTok = blockIdx.x * MT;

  // ---- phase 0: load x tile -> transposed fp32 residual cache (bit-exact copy) ----
  {
    const int tm = tid & 31, kp = tid >> 5;
    const float* xr = x + (size_t)(blockTok + tm) * DDIM;
#pragma unroll
    for (int i = 0; i < 16; ++i) {
      const int d4 = (kp + i * 8) << 2;
      const float4 v = *(const float4*)(xr + d4);
      r_t[(d4 + 0) * MT + tm] = v.x;
      r_t[(d4 + 1) * MT + tm] = v.y;
      r_t[(d4 + 2) * MT + tm] = v.z;
      r_t[(d4 + 3) * MT + tm] = v.w;
    }
  }
  __syncthreads();

  for (int qi = 0; qi < NQ; ++qi) {
    const float* cbq = cb + (size_t)qi * NCODES * DDIM;
    const float* enq = eef + qi * NCODES;

    // running per-token sorted top-4 (replicated across the 32 cg lanes of each tg)
    float cd[4][4]; int ci[4][4];
#pragma unroll
    for (int i = 0; i < 4; ++i)
#pragma unroll
      for (int s = 0; s < 4; ++s) { cd[i][s] = 3.0e38f; ci[i][s] = 0x7fffffff; }

    for (int chunk = 0; chunk < 4; ++chunk) {
      const int cbase = chunk << 8;
      float en[8];
#pragma unroll
      for (int j = 0; j < 8; ++j) {
        const int cl = (j < 4) ? (cg * 4 + j) : (128 + cg * 4 + (j - 4));
        en[j] = enq[cbase + cl];
      }
      float acc[4][8];
#pragma unroll
      for (int i = 0; i < 4; ++i)
#pragma unroll
        for (int j = 0; j < 8; ++j) acc[i][j] = 0.f;

      const float* grow = cbq + ((size_t)(cbase + tid) << 9);
      float4 v0 = *(const float4*)(grow + 0);
      float4 v1 = *(const float4*)(grow + 4);

      for (int kc = 0; kc < 64; ++kc) {
        const int k0 = kc << 3;
        __syncthreads();                      // previous compute done -> bt reusable
        bt[0 * NCHUNK + tid] = v0.x; bt[1 * NCHUNK + tid] = v0.y;
        bt[2 * NCHUNK + tid] = v0.z; bt[3 * NCHUNK + tid] = v0.w;
        bt[4 * NCHUNK + tid] = v1.x; bt[5 * NCHUNK + tid] = v1.y;
        bt[6 * NCHUNK + tid] = v1.z; bt[7 * NCHUNK + tid] = v1.w;
        {
          const int kn = (kc < 63) ? (k0 + 8) : k0;
          v0 = *(const float4*)(grow + kn);
          v1 = *(const float4*)(grow + kn + 4);
        }
        __syncthreads();                      // bt visible
#pragma unroll
        for (int kk = 0; kk < 8; ++kk) {
          const float4 a  = *(const float4*)&r_t[(k0 + kk) * MT + (tg << 2)];
          const float4 b0 = *(const float4*)&bt[kk * NCHUNK + (cg << 2)];
          const float4 b1 = *(const float4*)&bt[kk * NCHUNK + 128 + (cg << 2)];
          const float av[4] = {a.x, a.y, a.z, a.w};
          const float bv[8] = {b0.x, b0.y, b0.z, b0.w, b1.x, b1.y, b1.z, b1.w};
#pragma unroll
          for (int i = 0; i < 4; ++i)
#pragma unroll
            for (int j = 0; j < 8; ++j)
              acc[i][j] = fmaf(av[i], bv[j], acc[i][j]);
        }
      }

      // sorted-4 insertion of this chunk's 8 codes per token (screen distances)
#pragma unroll
      for (int i = 0; i < 4; ++i) {
#pragma unroll
        for (int j = 0; j < 8; ++j) {
          const int c = cbase + ((j < 4) ? (cg * 4 + j) : (128 + cg * 4 + (j - 4)));
          const float dd = en[j] - 2.0f * acc[i][j];
          if (better(dd, c, cd[i][3], ci[i][3])) {
            if (better(dd, c, cd[i][1], ci[i][1])) {
              if (better(dd, c, cd[i][0], ci[i][0])) {
                cd[i][3]=cd[i][2]; ci[i][3]=ci[i][2];
                cd[i][2]=cd[i][1]; ci[i][2]=ci[i][1];
                cd[i][1]=cd[i][0]; ci[i][1]=ci[i][0];
                cd[i][0]=dd; ci[i][0]=c;
              } else {
                cd[i][3]=cd[i][2]; ci[i][3]=ci[i][2];
                cd[i][2]=cd[i][1]; ci[i][2]=ci[i][1];
                cd[i][1]=dd; ci[i][1]=c;
              }
            } else {
              if (better(dd, c, cd[i][2], ci[i][2])) {
                cd[i][3]=cd[i][2]; ci[i][3]=ci[i][2];
                cd[i][2]=dd; ci[i][2]=c;
              } else { cd[i][3]=dd; ci[i][3]=c; }
            }
          }
        }
      }
    } // chunks

    // cross-lane bitonic merge of sorted-4 lists (disjoint code sets per lane)
#pragma unroll
    for (int i = 0; i < 4; ++i) {
#pragma unroll
      for (int m = 1; m <= 16; m <<= 1) {
        const float b0 = __shfl_xor(cd[i][0], m, 64), b1 = __shfl_xor(cd[i][1], m, 64),
                    b2 = __shfl_xor(cd[i][2], m, 64), b3 = __shfl_xor(cd[i][3], m, 64);
        const int   o0 = __shfl_xor(ci[i][0], m, 64), o1 = __shfl_xor(ci[i][1], m, 64),
                    o2 = __shfl_xor(ci[i][2], m, 64), o3 = __shfl_xor(ci[i][3], m, 64);
        float L0, L1, L2, L3; int M0, M1, M2, M3;
        if (better(b3, o3, cd[i][0], ci[i][0])) { L0 = b3; M0 = o3; } else { L0 = cd[i][0]; M0 = ci[i][0]; }
        if (better(b2, o2, cd[i][1], ci[i][1])) { L1 = b2; M1 = o2; } else { L1 = cd[i][1]; M1 = ci[i][1]; }
        if (better(b1, o1, cd[i][2], ci[i][2])) { L2 = b1; M2 = o1; } else { L2 = cd[i][2]; M2 = ci[i][2]; }
        if (better(b0, o0, cd[i][3], ci[i][3])) { L3 = b0; M3 = o0; } else { L3 = cd[i][3]; M3 = ci[i][3]; }
        if (better(L2, M2, L0, M0)) { float t=L0; L0=L2; L2=t; int u=M0; M0=M2; M2=u; }
        if (better(L3, M3, L1, M1)) { float t=L1; L1=L3; L3=t; int u=M1; M1=M3; M3=u; }
        if (better(L1, M1, L0, M0)) { float t=L0; L0=L1; L1=t; int u=M0; M0=M1; M1=u; }
        if (better(L3, M3, L2, M2)) { float t=L2; L2=L3; L3=t; int u=M2; M2=M3; M3=u; }
        cd[i][0]=L0; ci[i][0]=M0; cd[i][1]=L1; ci[i][1]=M1;
        cd[i][2]=L2; ci[i][2]=M2; cd[i][3]=L3; ci[i][3]=M3;
      }
    }
    if (cg == 0) {
#pragma unroll
      for (int i = 0; i < 4; ++i)
#pragma unroll
        for (int s = 0; s < 4; ++s) bcand[(tg * 4 + i) * 4 + s] = ci[i][s];
    }
    __syncthreads();

    // ---- faithful np-fp32 rescore of the 4 candidates ----
    // threads 0..127: token = tid>>2, cand slot = tid&3
    if (tid < 128) {
      const int tok4 = tid >> 2, cnd = tid & 3;
      // rr: numpy pairwise sum of fl(r*r) over 512 (tree: ((pw+pw)+(pw+pw)))
      float blk;
      {
        const int kb = cnd * 128;
        float a[8];
#pragma unroll
        for (int j = 0; j < 8; ++j) {
          const float v = r_t[(kb + j) * MT + tok4];
          a[j] = __fmul_rn(v, v);
        }
        for (int i = 8; i < 128; i += 8) {
#pragma unroll
          for (int j = 0; j < 8; ++j) {
            const float v = r_t[(kb + i + j) * MT + tok4];
            a[j] = __fadd_rn(a[j], __fmul_rn(v, v));
          }
        }
        blk = __fadd_rn(__fadd_rn(__fadd_rn(a[0], a[1]), __fadd_rn(a[2], a[3])),
                        __fadd_rn(__fadd_rn(a[4], a[5]), __fadd_rn(a[6], a[7])));
      }
      const float pw256 = __fadd_rn(blk, __shfl_xor(blk, 1, 64));
      const float rr    = __fadd_rn(pw256, __shfl_xor(pw256, 2, 64));

      // cross: sgemm-faithful sequential-k FMA chain, K split at KSPLIT
      const int cme = bcand[tok4 * 4 + cnd];
      const float* ep = cbq + (size_t)cme * DDIM;
      float Sa = 0.f, Sb = 0.f;
      for (int kb = 0; kb < DDIM; kb += 8) {
        const float4 e0 = *(const float4*)(ep + kb);
        const float4 e1 = *(const float4*)(ep + kb + 4);
        const float ev[8] = {e0.x, e0.y, e0.z, e0.w, e1.x, e1.y, e1.z, e1.w};
        float rv[8];
#pragma unroll
        for (int j = 0; j < 8; ++j) rv[j] = r_t[(kb + j) * MT + tok4];
        if (kb < KSPLIT) {
#pragma unroll
          for (int j = 0; j < 8; ++j) Sa = __fmaf_rn(rv[j], ev[j], Sa);
        } else {
#pragma unroll
          for (int j = 0; j < 8; ++j) Sb = __fmaf_rn(rv[j], ev[j], Sb);
        }
      }
      const float cross = __fadd_rn(Sa, Sb);
      // d = fl(fl(rr - 2*cross) + ee)   (reference combine order)
      const float u = __fsub_rn(rr, __fmul_rn(2.0f, cross));
      float d = __fadd_rn(u, enq[cme]);
      int   c = cme;
      // first-min over the 4 candidate lanes
#pragma unroll
      for (int m = 1; m <= 2; m <<= 1) {
        const float od = __shfl_xor(d, m, 64);
        const int   oc = __shfl_xor(c, m, 64);
        if (better(od, oc, d, c)) { d = od; c = oc; }
      }
      if (cnd == 0) {
        hist[tok4][qi] = c;
        outidx[(size_t)(blockTok + tok4) * NQ + qi] = (float)c;
      }
    }
    __syncthreads();

    // ---- faithful fp32 residual update + commit-loss sum ----
    const int wc = hist[tokR][qi];
    const float* ew = cbq + (size_t)wc * DDIM;
    double lssq = 0.0;
    for (int i = 0; i < 16; ++i) {
      const int d4 = (part + i * 8) << 2;
      const float4 qv = *(const float4*)(ew + d4);
      const float qa[4] = {qv.x, qv.y, qv.z, qv.w};
#pragma unroll
      for (int e = 0; e < 4; ++e) {
        const float r  = r_t[(d4 + e) * MT + tokR];
        const float a  = __fsub_rn(qa[e], r);       // fl(q - r)   (commit diff)
        const float qs = __fadd_rn(r, a);           // q_st = fl(r + (q-r))
        const float rn = __fsub_rn(r, qs);          // r' = fl(r - q_st)
        r_t[(d4 + e) * MT + tokR] = rn;
        lssq += (double)a * (double)a;
      }
    }
#pragma unroll
    for (int off = 32; off; off >>= 1) lssq += __shfl_down(lssq, off, 64);
    if ((tid & 63) == 0) wred[tid >> 6] = lssq;
    __syncthreads();
    if (tid == 0) atomicAdd(&lossAcc[qi], wred[0] + wred[1] + wred[2] + wred[3]);
  } // qi

  // ---- final: faithful fp32 replay -> quantized_out = sum of q_st per round ----
  {
    for (int i = 0; i < 16; ++i) {
      const int d4 = (part + i * 8) << 2;
      const float4 xv = *(const float4*)(x + (size_t)(blockTok + tokR) * DDIM + d4);
      float r[4]  = {xv.x, xv.y, xv.z, xv.w};
      float qa[4] = {0.f, 0.f, 0.f, 0.f};
#pragma unroll
      for (int j = 0; j < NQ; ++j) {
        const int hj = hist[tokR][j];
        const float4 ev = *(const float4*)(cb + ((size_t)j * NCODES + hj) * DDIM + d4);
        const float qv[4] = {ev.x, ev.y, ev.z, ev.w};
#pragma unroll
        for (int e = 0; e < 4; ++e) {
          const float a  = __fsub_rn(qv[e], r[e]);
          const float qs = __fadd_rn(r[e], a);
          r[e]  = __fsub_rn(r[e], qs);
          qa[e] = __fadd_rn(qa[e], qs);
        }
      }
      float4 pk; pk.x = qa[0]; pk.y = qa[1]; pk.z = qa[2]; pk.w = qa[3];
      *(float4*)(outq + (size_t)(blockTok + tokR) * DDIM + d4) = pk;
    }
  }
}

// ---------------- losses finalize ----------------
__global__ void loss_fin(const double* __restrict__ lossAcc,
                         float* __restrict__ outLoss,
                         float* __restrict__ outTot) {
  if (threadIdx.x == 0 && blockIdx.x == 0) {
    double tot = 0.0;
    for (int qi = 0; qi < NQ; ++qi) {
      const double v = lossAcc[qi] * (COMMIT_W / ((double)TOKENS * (double)DDIM));
      outLoss[qi] = (float)v;
      tot += v;
    }
    *outTot = (float)tot;
  }
}

extern "C" void kernel_launch(void* const* d_in, const int* in_sizes, int n_in,
                              void* d_out, int out_size, void* d_ws, size_t ws_size,
                              hipStream_t stream) {
  const float* x  = (const float*)d_in[0];
  const float* cb = (const float*)d_in[1];
  float* out = (float*)d_out;

  double* lossAcc = (double*)d_ws;                      // 8 f64
  float*  eef     = (float*)((char*)d_ws + 256);        // 8192 f32 (np-faithful ||e||^2)

  prep_kernel<<<dim3(32), dim3(256), 0, stream>>>(cb, eef, lossAcc);
  rvq_main<<<dim3(NBLOCKS), dim3(256), 0, stream>>>(x, cb, eef, lossAcc,
                                                    out, out + OFF_IDX);
  loss_fin<<<dim3(1), dim3(64), 0, stream>>>(lossAcc, out + OFF_LOSS, out + OFF_TOT);
}